// Round 1
// 273.579 us; speedup vs baseline: 1.0758x; 1.0758x over previous
//
#include <hip/hip_runtime.h>
#include <hip/hip_bf16.h>

// GCNBlock: 9-dispatch pipeline, parallel scan, single atomic pass.
// h' = (x@W)*dinv stored bf16 ; gather-aggregate ; graph-LayerNorm ; PReLU
// N=50000, E=800000, F=256
//
// R1 change: gemm half of fill_gemm restructured from 16-row tiles with
// per-lane scattered x loads (VMEM-request bound, MfmaUtil 3.4%) to 64-row
// tiles with coalesced LDS-staged A ([64][264] pad-8 -> conflict-free
// ds_read_b128 fragments) and 4x fewer Wb passes (400MB -> 100MB L2).

#define F 256
#define EPSV 1e-5f

typedef __attribute__((ext_vector_type(8))) short short8;
typedef __attribute__((ext_vector_type(4))) float f32x4;

__device__ __forceinline__ unsigned short f2bf(float f) {
  union { float f; unsigned u; } v; v.f = f;
  unsigned r = v.u + 0x7fffu + ((v.u >> 16) & 1u);  // RNE
  return (unsigned short)(r >> 16);
}

__device__ __forceinline__ float bf2f(unsigned short u) {
  union { unsigned u; float f; } v; v.u = ((unsigned)u) << 16; return v.f;
}

// ---- count + rank (edges) ; prep_W (blocks >= eb) --------------------------
// rank[e] = this edge's arrival index among edges with same dst -> fill needs no atomics.

__global__ void count_rank(const int* __restrict__ dst, int* __restrict__ deg_cnt,
                           int* __restrict__ rank, int E, int eb,
                           const float* __restrict__ W, unsigned short* __restrict__ Wb) {
  if ((int)blockIdx.x < eb) {
    int e = blockIdx.x * 256 + threadIdx.x;
    if (e < E) rank[e] = atomicAdd(&deg_cnt[dst[e]], 1);
    return;
  }
  int gid = (blockIdx.x - eb) * 256 + threadIdx.x;  // 65536 total
  int j = gid & 7;
  int lane = (gid >> 3) & 63;
  int kc = (gid >> 9) & 7;
  int tt = gid >> 12;
  int k = kc * 32 + (lane >> 4) * 8 + j;
  int n = tt * 16 + (lane & 15);
  Wb[gid] = f2bf(W[k * 256 + n]);
}

// ---- parallel scan chain (3 small kernels) ---------------------------------

__global__ void block_sums(const int* __restrict__ deg_cnt, int* __restrict__ bsum,
                           float* __restrict__ dinv, int N) {
  __shared__ int s[256];
  int t = threadIdx.x;
  int i = blockIdx.x * 256 + t;
  int d = (i < N) ? deg_cnt[i] : 0;
  if (i < N) dinv[i] = rsqrtf((float)(d + 1));  // +1 self loop
  s[t] = d;
  __syncthreads();
  for (int off = 128; off > 0; off >>= 1) {
    if (t < off) s[t] += s[t + off];
    __syncthreads();
  }
  if (t == 0) bsum[blockIdx.x] = s[0];
}

__global__ void scan_bsums(const int* __restrict__ bsum, int* __restrict__ boff, int nb) {
  __shared__ int s[256];
  int t = threadIdx.x;
  int v = (t < nb) ? bsum[t] : 0;
  s[t] = v;
  __syncthreads();
  for (int off = 1; off < 256; off <<= 1) {
    int x = (t >= off) ? s[t - off] : 0;
    __syncthreads();
    s[t] += x;
    __syncthreads();
  }
  if (t < nb) boff[t] = s[t] - v;  // exclusive
}

__global__ void write_csr(const int* __restrict__ deg_cnt, const int* __restrict__ boff,
                          int* __restrict__ csr_ptr, int N, int E) {
  __shared__ int s[256];
  int t = threadIdx.x;
  int i = blockIdx.x * 256 + t;
  int v = (i < N) ? deg_cnt[i] : 0;
  s[t] = v;
  __syncthreads();
  for (int off = 1; off < 256; off <<= 1) {
    int x = (t >= off) ? s[t - off] : 0;
    __syncthreads();
    s[t] += x;
    __syncthreads();
  }
  if (i < N) csr_ptr[i] = boff[blockIdx.x] + s[t] - v;
  if (i == 0) csr_ptr[N] = E;
}

// ---- fill (atomic-free, blocks < eb) ; gemm 64-row tiles (blocks >= eb) ----

__global__ void fill_gemm(const int* __restrict__ src, const int* __restrict__ dst,
                          const int* __restrict__ rank, const int* __restrict__ csr_ptr,
                          int* __restrict__ csr_src, int E, int eb,
                          const float* __restrict__ x, const unsigned short* __restrict__ Wb,
                          const float* __restrict__ dinv, ushort4* __restrict__ hb, int N) {
  // A-tile staging AND epilogue repack share this buffer.
  // +8 pad: row stride 528B = 33*16B -> rows offset by 4 banks ->
  // ds_read_b128 of 16 rows at same col hits 8 distinct 4-bank groups (free).
  __shared__ unsigned short A[64][264];  // 33792 B -> 4 blocks/CU

  if ((int)blockIdx.x < eb) {
    int e = blockIdx.x * 256 + threadIdx.x;
    if (e < E) {
      int d = dst[e];
      csr_src[csr_ptr[d] + rank[e]] = src[e];
    }
    return;
  }

  int bid = blockIdx.x - eb;
  int m0 = bid * 64;
  int t = threadIdx.x;
  int lane = t & 63;
  int wave = t >> 6;
  int q = lane >> 4;

  // ---- stage A: 64 rows x 256 cols, fp32 -> bf16, fully coalesced ----------
#pragma unroll
  for (int j = 0; j < 16; ++j) {
    int idx = j * 256 + t;      // 0..4095 float4s
    int row = idx >> 6;         // 0..63
    int c4 = idx & 63;          // float4 within row
    int gr = m0 + row;
    int grc = gr < N ? gr : N - 1;
    float4 v = *(const float4*)(x + (size_t)grc * F + c4 * 4);
    ushort4 u;
    u.x = f2bf(v.x); u.y = f2bf(v.y); u.z = f2bf(v.z); u.w = f2bf(v.w);
    *(ushort4*)&A[row][c4 * 4] = u;
  }
  __syncthreads();

  // ---- compute: each wave owns 64 rows x 64 cols (4 m-tiles x 4 n-tiles) ---
  f32x4 acc[4][4];
#pragma unroll
  for (int m = 0; m < 4; ++m)
#pragma unroll
    for (int tt = 0; tt < 4; ++tt)
      acc[m][tt] = (f32x4){0.f, 0.f, 0.f, 0.f};

  int arow = lane & 15;
  for (int kc = 0; kc < 8; ++kc) {
    short8 a[4];
#pragma unroll
    for (int m = 0; m < 4; ++m)
      a[m] = *(const short8*)&A[m * 16 + arow][kc * 32 + q * 8];
#pragma unroll
    for (int tt = 0; tt < 4; ++tt) {
      const short8 b = *(const short8*)(Wb + (((wave * 4 + tt) * 8 + kc) * 64 + lane) * 8);
#pragma unroll
      for (int m = 0; m < 4; ++m)
        acc[m][tt] = __builtin_amdgcn_mfma_f32_16x16x32_bf16(a[m], b, acc[m][tt], 0, 0, 0);
    }
  }

  __syncthreads();  // all waves done reading A before repack overwrites it

  // ---- epilogue: scale by dinv, bf16, repack via LDS, coalesced store ------
  int ccol = lane & 15;
#pragma unroll
  for (int m = 0; m < 4; ++m) {
#pragma unroll
    for (int rr = 0; rr < 4; ++rr) {
      int lrow = m * 16 + q * 4 + rr;
      int orow = m0 + lrow;
      float dv = (orow < N) ? dinv[orow] : 0.f;
#pragma unroll
      for (int tt = 0; tt < 4; ++tt)
        A[lrow][(wave * 4 + tt) * 16 + ccol] = f2bf(acc[m][tt][rr] * dv);
    }
  }
  __syncthreads();
#pragma unroll
  for (int j = 0; j < 16; ++j) {
    int idx = j * 256 + t;
    int row = idx >> 6;
    int c4 = idx & 63;
    int grow = m0 + row;
    if (grow < N) hb[(size_t)grow * 64 + c4] = *(const ushort4*)&A[row][c4 * 4];
  }
}

// ---- Aggregation: one row per wave, 16-way unrolled bf16 gather ------------

__global__ void aggregate(const ushort4* __restrict__ hb, const int* __restrict__ csr_ptr,
                          const int* __restrict__ csr_src, const float* __restrict__ dinv,
                          const float* __restrict__ conv_bias, float4* __restrict__ out,
                          double2* __restrict__ partials, int N) {
  int wave = threadIdx.x >> 6;
  int lane = threadIdx.x & 63;
  int row = blockIdx.x * 4 + wave;
  float s1 = 0.f, s2 = 0.f;

  if (row < N) {
    float di = dinv[row];
    int b0 = csr_ptr[row], b1 = csr_ptr[row + 1];
    ushort4 self = hb[(size_t)row * 64 + lane];
    float4 acc;
    acc.x = bf2f(self.x); acc.y = bf2f(self.y);
    acc.z = bf2f(self.z); acc.w = bf2f(self.w);

    for (int e = b0; e < b1; e += 16) {
      int idx[16];
#pragma unroll
      for (int j = 0; j < 16; ++j) {
        int ee = e + j;
        idx[j] = csr_src[ee < b1 ? ee : b1 - 1];
      }
      ushort4 v[16];
#pragma unroll
      for (int j = 0; j < 16; ++j) v[j] = hb[(size_t)idx[j] * 64 + lane];
#pragma unroll
      for (int j = 0; j < 16; ++j) {
        float m = (e + j < b1) ? 1.f : 0.f;
        acc.x = fmaf(bf2f(v[j].x), m, acc.x);
        acc.y = fmaf(bf2f(v[j].y), m, acc.y);
        acc.z = fmaf(bf2f(v[j].z), m, acc.z);
        acc.w = fmaf(bf2f(v[j].w), m, acc.w);
      }
    }

    float4 b = *(const float4*)(conv_bias + lane * 4);
    acc.x = fmaf(acc.x, di, b.x);
    acc.y = fmaf(acc.y, di, b.y);
    acc.z = fmaf(acc.z, di, b.z);
    acc.w = fmaf(acc.w, di, b.w);
    out[(size_t)row * 64 + lane] = acc;
    s1 = acc.x + acc.y + acc.z + acc.w;
    s2 = acc.x * acc.x + acc.y * acc.y + acc.z * acc.z + acc.w * acc.w;
  }

  __shared__ float r1[256];
  __shared__ float r2[256];
  int t = threadIdx.x;
  r1[t] = s1;
  r2[t] = s2;
  __syncthreads();
  for (int off = 128; off > 0; off >>= 1) {
    if (t < off) { r1[t] += r1[t + off]; r2[t] += r2[t + off]; }
    __syncthreads();
  }
  if (t == 0) {
    double2 pp;
    pp.x = (double)r1[0];
    pp.y = (double)r2[0];
    partials[blockIdx.x] = pp;
  }
}

__global__ void finalize_stats(const double2* __restrict__ partials, int nb,
                               float* __restrict__ stats, double cnt) {
  __shared__ double q1[1024];
  __shared__ double q2[1024];
  int t = threadIdx.x;
  double a1 = 0.0, a2 = 0.0;
  for (int i = t; i < nb; i += 1024) {
    double2 pp = partials[i];
    a1 += pp.x;
    a2 += pp.y;
  }
  q1[t] = a1;
  q2[t] = a2;
  __syncthreads();
  for (int off = 512; off > 0; off >>= 1) {
    if (t < off) { q1[t] += q1[t + off]; q2[t] += q2[t + off]; }
    __syncthreads();
  }
  if (t == 0) {
    double mu = q1[0] / cnt;
    double var = q2[0] / cnt - mu * mu;
    if (var < 0) var = 0;
    double sd = sqrt(var);
    stats[0] = (float)mu;
    stats[1] = (float)(1.0 / (sd + (double)EPSV));
  }
}

__global__ void norm_prelu(float4* __restrict__ out, const float* __restrict__ stats,
                           const float* __restrict__ lw, const float* __restrict__ lb,
                           const float* __restrict__ pa, int n4) {
  int i = blockIdx.x * blockDim.x + threadIdx.x;
  if (i >= n4) return;
  float mu = stats[0];
  float inv = stats[1];
  float a = pa[0];
  int c4 = (i & 63) * 4;
  float4 w = *(const float4*)(lw + c4);
  float4 b = *(const float4*)(lb + c4);
  float4 v = out[i];
  float y0 = (v.x - mu) * inv * w.x + b.x;
  float y1 = (v.y - mu) * inv * w.y + b.y;
  float y2 = (v.z - mu) * inv * w.z + b.z;
  float y3 = (v.w - mu) * inv * w.w + b.w;
  v.x = y0 >= 0.f ? y0 : a * y0;
  v.y = y1 >= 0.f ? y1 : a * y1;
  v.z = y2 >= 0.f ? y2 : a * y2;
  v.w = y3 >= 0.f ? y3 : a * y3;
  out[i] = v;
}

// ---- launch ---------------------------------------------------------------

extern "C" void kernel_launch(void* const* d_in, const int* in_sizes, int n_in,
                              void* d_out, int out_size, void* d_ws, size_t ws_size,
                              hipStream_t stream) {
  const float* x = (const float*)d_in[0];
  const int* eidx = (const int*)d_in[1];
  const float* W = (const float*)d_in[3];
  const float* conv_bias = (const float*)d_in[4];
  const float* ln_w = (const float*)d_in[5];
  const float* ln_b = (const float*)d_in[6];
  const float* prelu_a = (const float*)d_in[7];
  float* out = (float*)d_out;

  int N = in_sizes[0] / F;
  int E = in_sizes[1] / 2;
  const int* src = eidx;
  const int* dst = eidx + E;

  int nAggBlocks = (N + 3) / 4;
  int eb = (E + 255) / 256;
  int gemmb = (N + 63) / 64;
  int NB = (N + 255) / 256;

  char* p = (char*)d_ws;
  auto carve = [&](size_t bytes) { char* r = p; p += (bytes + 255) & ~(size_t)255; return r; };
  ushort4* hb    = (ushort4*)carve((size_t)N * 64 * sizeof(ushort4));  // bf16 h'
  unsigned short* Wb = (unsigned short*)carve((size_t)F * F * sizeof(short));
  int* deg_cnt   = (int*)carve((size_t)N * sizeof(int));
  int* rank      = (int*)carve((size_t)E * sizeof(int));
  float* dinv    = (float*)carve((size_t)N * sizeof(float));
  int* csr_ptr   = (int*)carve((size_t)(N + 1) * sizeof(int));
  int* csr_src   = (int*)carve((size_t)E * sizeof(int));
  int* bsum      = (int*)carve((size_t)NB * sizeof(int));
  int* boff      = (int*)carve((size_t)NB * sizeof(int));
  double2* partials = (double2*)carve((size_t)nAggBlocks * sizeof(double2));
  float* stats   = (float*)carve(2 * sizeof(float));

  hipMemsetAsync(deg_cnt, 0, (size_t)N * sizeof(int), stream);

  count_rank<<<eb + 256, 256, 0, stream>>>(dst, deg_cnt, rank, E, eb, W, Wb);
  block_sums<<<NB, 256, 0, stream>>>(deg_cnt, bsum, dinv, N);
  scan_bsums<<<1, 256, 0, stream>>>(bsum, boff, NB);
  write_csr<<<NB, 256, 0, stream>>>(deg_cnt, boff, csr_ptr, N, E);
  fill_gemm<<<eb + gemmb, 256, 0, stream>>>(src, dst, rank, csr_ptr, csr_src, E, eb,
                                            x, Wb, dinv, hb, N);
  aggregate<<<nAggBlocks, 256, 0, stream>>>(hb, csr_ptr, csr_src, dinv,
                                            conv_bias, (float4*)out, partials, N);
  finalize_stats<<<1, 1024, 0, stream>>>(partials, nAggBlocks, stats,
                                         (double)N * (double)F);
  int n4 = N * (F / 4);
  norm_prelu<<<(n4 + 255) / 256, 256, 0, stream>>>((float4*)out, stats, ln_w, ln_b, prelu_a, n4);
}